// Round 14
// baseline (851.749 us; speedup 1.0000x reference)
//
#include <hip/hip_runtime.h>
#include <hip/hip_bf16.h>

#define B_ 8
#define D_ 40
#define T_ 192
#define G_ 256
#define U_ 768   // 3*UNITS
#define H_ 256   // UNITS
#define XSTEP 6144   // f16 x-values per grid step: 16n*16jl*3gate*8b

typedef int v4i __attribute__((ext_vector_type(4)));
typedef float f32x4 __attribute__((ext_vector_type(4)));
typedef _Float16 f16x4 __attribute__((ext_vector_type(4)));

__device__ inline float sigmoidf_(float x){
  return 1.0f/(1.0f+__expf(-x));
}
__device__ inline float tanhf_(float x){
  float ax = fabsf(x);
  float e = __expf(-2.0f*ax);
  float t = (1.0f-e)/(1.0f+e);
  return copysignf(t, x);
}
__device__ inline int pack4(int q0,int q1,int q2,int q3){
  return (q0&255) | ((q1&255)<<8) | ((q2&255)<<16) | ((q3&255)<<24);
}
__device__ inline v4i mfma_i8(v4i a, v4i b, v4i c){
#if __has_builtin(__builtin_amdgcn_mfma_i32_16x16x64_i8)
  return __builtin_amdgcn_mfma_i32_16x16x64_i8(a, b, c, 0, 0, 0);
#else
  v4i d;
  asm volatile("v_mfma_i32_16x16x64_i8 %0, %1, %2, %3\n\ts_nop 7\n\ts_nop 7"
               : "=v"(d) : "v"(a), "v"(b), "v"(c));
  return d;
#endif
}

// ---------------- Kernel 1: single-channel interp + per-(b,d) mean ----------
__global__ __launch_bounds__(256) void k_interp(
    const float* __restrict__ times, const float* __restrict__ values,
    const float* __restrict__ meas, const float* __restrict__ grid,
    const float* __restrict__ ksic,
    float* __restrict__ y, float* __restrict__ w, float* __restrict__ ytr,
    float* __restrict__ mean){
  int bd = blockIdx.x;            // b*D_+d
  int b = bd / D_, d = bd % D_;
  int g = threadIdx.x;
  __shared__ float tt[T_], vv[T_], mm[T_];
  __shared__ float red[256];
  if (g < T_){
    tt[g] = times[bd*T_+g];
    vv[g] = values[bd*T_+g];
    mm[g] = meas[bd*T_+g];
  }
  __syncthreads();
  float alpha = log1pf(__expf(ksic[d]));   // softplus
  float tg = grid[b*G_+g];
  float nmin = 3.4e38f;
  for (int t=0;t<T_;t++){
    if (mm[t] > 0.0f){
      float dd = tt[t]-tg;
      nmin = fminf(nmin, dd*dd);
    }
  }
  float s1=0.f, sv1=0.f, s10=0.f, sv10=0.f;
  for (int t=0;t<T_;t++){
    if (mm[t] > 0.0f){
      float dd = tt[t]-tg;
      float n = dd*dd - nmin;               // >= 0
      float e1  = __expf(-alpha*n);
      float e10 = __expf(-10.0f*alpha*n);
      s1 += e1;  sv1 += e1*vv[t];
      s10 += e10; sv10 += e10*vv[t];
    }
  }
  float yv = sv1/s1;
  float wv = -alpha*nmin + __logf(s1);
  y[bd*G_+g]   = yv;
  w[bd*G_+g]   = wv;
  ytr[bd*G_+g] = sv10/s10;
  red[g] = yv;
  __syncthreads();
  for (int s=128;s>0;s>>=1){
    if (g<s) red[g]+=red[g+s];
    __syncthreads();
  }
  if (g==0) mean[bd] = red[0]*(1.0f/(float)G_);
}

// ------- Kernel 2: cross-channel + feats + x_proj (4 g/block, f16 xls) ------
// Writes xls[g][n][jl][gate][b] (f16) with recurrent biases brz/brr folded in
// (additive outside the reset gate; brh stays inside r*(...) in k_gru).
__global__ __launch_bounds__(256) void k_cross(
    const float* __restrict__ y, const float* __restrict__ w,
    const float* __restrict__ ytr, const float* __restrict__ mean,
    const float* __restrict__ crossW, const float* __restrict__ Wx,
    const float* __restrict__ gru_b, const int* __restrict__ lens,
    _Float16* __restrict__ xls){
  int blk = blockIdx.x;             // b*64 + gq
  int b = blk >> 6, gq = blk & 63;
  int g0 = gq*4;
  if (g0 >= lens[b]) return;        // whole quad unused (frozen in k_gru)
  __shared__ float wd[4][D_], yd[4][D_], ytrd[4][D_], md[D_];
  __shared__ float cc4[4][D_], feats[4][3*D_];
  __shared__ float wstat[4][2];
  int tid = threadIdx.x;
  int gg = tid / D_;
  int d  = tid % D_;
  if (tid < 4*D_){
    int idx = (b*D_+d)*G_ + g0 + gg;
    wd[gg][d]=w[idx]; yd[gg][d]=y[idx]; ytrd[gg][d]=ytr[idx];
  }
  if (tid < D_) md[tid] = mean[b*D_+tid];
  __syncthreads();
  if (tid < 4){
    float mx=-3.4e38f;
    for (int d2=0;d2<D_;d2++) mx = fmaxf(mx, wd[tid][d2]);
    float s=0.f;
    for (int d2=0;d2<D_;d2++) s += __expf(wd[tid][d2]-mx);
    wstat[tid][0]=mx; wstat[tid][1]=1.0f/s;
  }
  __syncthreads();
  if (tid < 4*D_){
    float sw = __expf(wd[gg][d]-wstat[gg][0])*wstat[gg][1];
    cc4[gg][d] = sw*(yd[gg][d]-md[d]);
  }
  __syncthreads();
  if (tid < 4*D_){
    float acc=0.f;
    for (int d2=0;d2<D_;d2++) acc += cc4[gg][d2]*crossW[d2*D_+d];
    float rep = acc + md[d];
    feats[gg][d]       = rep;
    feats[gg][D_+d]    = __expf(wd[gg][d]);
    feats[gg][2*D_+d]  = ytrd[gg][d]-rep;
  }
  __syncthreads();
  int n = tid >> 4, jl2 = tid & 15;
  for (int jj=0;jj<3;jj++){
    int colg = jj*256 + tid;
    float bi = gru_b[colg] + ((jj<2)? gru_b[U_+colg] : 0.0f);  // fold brz/brr
    float a0=bi, a1=bi, a2=bi, a3=bi;
    #pragma unroll 4
    for (int i=0;i<3*D_;i++){
      float wv = Wx[i*U_+colg];     // one load feeds 4 g's
      a0 += feats[0][i]*wv;
      a1 += feats[1][i]*wv;
      a2 += feats[2][i]*wv;
      a3 += feats[3][i]*wv;
    }
    size_t off = (size_t)(n*16 + jl2)*24 + jj*8 + b;
    xls[(size_t)(g0+0)*XSTEP + off] = (_Float16)a0;
    xls[(size_t)(g0+1)*XSTEP + off] = (_Float16)a1;
    xls[(size_t)(g0+2)*XSTEP + off] = (_Float16)a2;
    xls[(size_t)(g0+3)*XSTEP + off] = (_Float16)a3;
  }
}

// ---------------- Kernel 3: demo MLP -> h0 ----------------------------------
__global__ __launch_bounds__(256) void k_demo(
    const float* __restrict__ demo, const float* __restrict__ W1,
    const float* __restrict__ b1, const float* __restrict__ W2,
    const float* __restrict__ b2, float* __restrict__ h0){
  __shared__ float dl[B_*16];
  __shared__ float hid[B_*H_];
  int u = threadIdx.x;
  if (u < B_*16) dl[u] = demo[u];
  __syncthreads();
  float acc[B_];
  #pragma unroll
  for (int b=0;b<B_;b++) acc[b]=b1[u];
  for (int i=0;i<16;i++){
    float w1 = W1[i*H_+u];
    #pragma unroll
    for (int b=0;b<B_;b++) acc[b] += dl[b*16+i]*w1;
  }
  #pragma unroll
  for (int b=0;b<B_;b++) hid[b*H_+u] = fmaxf(acc[b],0.f);
  __syncthreads();
  #pragma unroll
  for (int b=0;b<B_;b++) acc[b]=b2[u];
  for (int k=0;k<H_;k++){
    float w2 = W2[k*H_+u];
    #pragma unroll
    for (int b=0;b<B_;b++) acc[b] += hid[b*H_+k]*w2;
  }
  #pragma unroll
  for (int b=0;b<B_;b++) h0[b*H_+u]=acc[b];
}

// ------- Kernel 3b: quantize Wh -> int8 B-FRAGMENTS for mfma 16x16x64 -------
// wfrag[n][gate][kk][lane][dw]: lane holds col = gate*256+16n+(lane&15),
// k = 64kk + (lane>>4)*16 + 4dw + byte  (same lane->k map the A-read uses, so
// any deviation from HW's internal k order cancels between A and B).
__global__ __launch_bounds__(256) void k_quant(
    const float* __restrict__ Wh, int* __restrict__ wfrag,
    float* __restrict__ wmaxs){
  int bid = blockIdx.x;            // 12 blocks x 64 cols
  int c0 = bid*64;
  int gate = c0 >> 8;
  int n0 = (c0 & 255) >> 4;
  __shared__ float cm[4][64];
  __shared__ float mcomb[64];
  {
    int rg = threadIdx.x >> 6, cc = threadIdx.x & 63;
    int col = c0 + cc;
    float mx = 0.f;
    for (int r = 0; r < 64; r++)
      mx = fmaxf(mx, fabsf(Wh[(size_t)(rg*64+r)*U_ + col]));
    cm[rg][cc] = mx;
  }
  __syncthreads();
  if (threadIdx.x < 64){
    int cc = threadIdx.x;
    float m = fmaxf(fmaxf(cm[0][cc],cm[1][cc]), fmaxf(cm[2][cc],cm[3][cc]));
    mcomb[cc] = m;
    wmaxs[c0+cc] = m;
  }
  __syncthreads();
  int nn = threadIdx.x >> 6;       // 0..3
  int L  = threadIdx.x & 63;
  int jl = L & 15, qq = L >> 4;
  int col = c0 + 16*nn + jl;
  float m = mcomb[16*nn + jl];
  float iw = (m > 0.f) ? 127.0f/m : 0.f;
  int n = n0 + nn;
  #pragma unroll
  for (int kk = 0; kk < 4; kk++){
    #pragma unroll
    for (int dw = 0; dw < 4; dw++){
      int k0 = 64*kk + qq*16 + 4*dw;
      int qa = (int)rintf(Wh[(size_t)(k0+0)*U_+col]*iw);
      int qb = (int)rintf(Wh[(size_t)(k0+1)*U_+col]*iw);
      int qc = (int)rintf(Wh[(size_t)(k0+2)*U_+col]*iw);
      int qd = (int)rintf(Wh[(size_t)(k0+3)*U_+col]*iw);
      wfrag[(((n*3+gate)*4+kk)*64 + L)*4 + dw] = pack4(qa,qb,qc,qd);
    }
  }
}

// ---------------- Kernel 4: masked GRU via i8 MFMA, ALL batches, 1 block ----
// 256 threads / 4 waves / grid 1. Wave w owns triplets n in [4w,4w+4)
// (units 16n..16n+16; z/r/h cols). Per step: D[16,768] = A(h,i8)[16,256] x
// B(Wh,i8) via 48 mfma_i32_16x16x64_i8 per wave. D layout (HW-verified):
// col=lane&15, row(batch)=(lane>>4)*4+reg. A: row=lane&15 (batch),
// k=(lane>>4)*16+byte within 64k-inst. h f32 state in LDS (no quantization
// error accumulation: dot uses fresh Q(h) each step). x staged f16 in LDS,
// double-buffered, one barrier/step. Per-batch freeze g>=len via cndmask.
__global__ __attribute__((amdgpu_flat_work_group_size(256,256), amdgpu_waves_per_eu(1,1)))
void k_gru(
    const int* __restrict__ wfrag, const float* __restrict__ wmaxs,
    const float* __restrict__ gru_b, const _Float16* __restrict__ xls,
    const float* __restrict__ h0, const int* __restrict__ lens,
    const float* __restrict__ outW, const float* __restrict__ outb,
    float* __restrict__ out){
  int tid = threadIdx.x;
  int w = tid >> 6, L = tid & 63;
  int jl = L & 15, q2 = L >> 4;     // lane quarter
  int qh = q2 & 1;                  // batch-half select (0: b0-3, 1: b4-7)

  __shared__ _Float16 xbuf[2][XSTEP];            // 24KB, double-buffered x
  __shared__ signed char hqs[2][16][272];        // i8 h, padded rows, 8.7KB
  __shared__ __align__(16) float hf[256][8];     // f32 h state [j][b], 8KB
  __shared__ float shsA[8][2];                   // [b]{inv_sh, s_h}
  __shared__ float redq[8][64];

  // zero hq (incl. pad rows 8-15, never rewritten)
  for (int i = tid; i < (int)(2*16*272/4); i += 256) ((int*)hqs)[i] = 0;

  // per-batch h0 absmax -> fixed scale (|h_new| <= max(|h_old|,1))
  if (tid < 8){
    float m = 0.f;
    for (int j = 0; j < H_; j++) m = fmaxf(m, fabsf(h0[tid*H_ + j]));
    float bound = fmaxf(m, 1.0f);
    shsA[tid][0] = 127.0f/bound;
    shsA[tid][1] = bound/127.0f;
  }
  __syncthreads();

  // init h state + quantized h buffer 0
  {
    int j = tid;
    #pragma unroll
    for (int b = 0; b < 8; b++){
      float h = h0[b*H_ + j];
      hf[j][b] = h;
      float qf = fmaxf(-127.f, fminf(127.f, rintf(h*shsA[b][0])));
      hqs[0][b][j] = (signed char)(int)qf;
    }
  }

  // weight B-fragments into registers (192 dwords; MFMA reads AGPR natively)
  v4i wreg[4][3][4];
  #pragma unroll
  for (int t = 0; t < 4; t++){
    int n = w*4 + t;
    #pragma unroll
    for (int gg = 0; gg < 3; gg++){
      #pragma unroll
      for (int kk = 0; kk < 4; kk++){
        wreg[t][gg][kk] = *(const v4i*)(wfrag + (((n*3+gg)*4+kk)*64 + L)*4);
      }
    }
  }
  // per-triplet dequant factors + brh
  float fz[4], fr2[4], fh2[4], brh[4];
  #pragma unroll
  for (int t = 0; t < 4; t++){
    int j = 16*(w*4+t) + jl;
    fz[t]  = wmaxs[j]      * (1.0f/127.0f);
    fr2[t] = wmaxs[H_+j]   * (1.0f/127.0f);
    fh2[t] = wmaxs[2*H_+j] * (1.0f/127.0f);
    brh[t] = gru_b[U_ + 2*H_ + j];
  }
  float shv[4], ishv[4]; int lenv[4];
  #pragma unroll
  for (int rr = 0; rr < 4; rr++){
    int b = qh*4 + rr;
    shv[rr]  = shsA[b][1];
    ishv[rr] = shsA[b][0];
    lenv[rr] = lens[b];
  }

  // stage x(0)
  {
    const _Float16* src = xls + (size_t)w*1536 + L*8;
    f16x4 r0=*(const f16x4*)(src),      r1=*(const f16x4*)(src+4);
    f16x4 r2=*(const f16x4*)(src+512),  r3=*(const f16x4*)(src+516);
    f16x4 r4=*(const f16x4*)(src+1024), r5=*(const f16x4*)(src+1028);
    _Float16* dst = &xbuf[0][w*1536 + L*8];
    *(f16x4*)(dst)=r0;      *(f16x4*)(dst+4)=r1;
    *(f16x4*)(dst+512)=r2;  *(f16x4*)(dst+516)=r3;
    *(f16x4*)(dst+1024)=r4; *(f16x4*)(dst+1028)=r5;
  }
  __syncthreads();

  int cur = 0;
  for (int g = 0; g < G_; g++){
    int nxt = cur ^ 1;
    // prefetch x(g+1) into regs (landed in LDS at end of step)
    f16x4 xr0,xr1,xr2,xr3,xr4,xr5;
    {
      int gn = (g+1 < G_) ? g+1 : g;
      const _Float16* src = xls + (size_t)gn*XSTEP + w*1536 + L*8;
      xr0=*(const f16x4*)(src);      xr1=*(const f16x4*)(src+4);
      xr2=*(const f16x4*)(src+512);  xr3=*(const f16x4*)(src+516);
      xr4=*(const f16x4*)(src+1024); xr5=*(const f16x4*)(src+1028);
    }
    // A fragments for the 4 K-instructions (row=lane&15, k-window per kk)
    v4i a0 = *(const v4i*)(&hqs[cur][jl][q2*16]);
    v4i a1 = *(const v4i*)(&hqs[cur][jl][64 + q2*16]);
    v4i a2 = *(const v4i*)(&hqs[cur][jl][128 + q2*16]);
    v4i a3 = *(const v4i*)(&hqs[cur][jl][192 + q2*16]);

    #pragma unroll
    for (int t = 0; t < 4; t++){
      v4i accz = {0,0,0,0}, accr = {0,0,0,0}, acch = {0,0,0,0};
      accz = mfma_i8(a0, wreg[t][0][0], accz);
      accz = mfma_i8(a1, wreg[t][0][1], accz);
      accz = mfma_i8(a2, wreg[t][0][2], accz);
      accz = mfma_i8(a3, wreg[t][0][3], accz);
      accr = mfma_i8(a0, wreg[t][1][0], accr);
      accr = mfma_i8(a1, wreg[t][1][1], accr);
      accr = mfma_i8(a2, wreg[t][1][2], accr);
      accr = mfma_i8(a3, wreg[t][1][3], accr);
      acch = mfma_i8(a0, wreg[t][2][0], acch);
      acch = mfma_i8(a1, wreg[t][2][1], acch);
      acch = mfma_i8(a2, wreg[t][2][2], acch);
      acch = mfma_i8(a3, wreg[t][2][3], acch);

      const _Float16* xb = &xbuf[cur][(size_t)w*1536 + (t*16 + jl)*24];
      f16x4 xz4 = *(const f16x4*)(xb + 0*8 + qh*4);
      f16x4 xr4g= *(const f16x4*)(xb + 1*8 + qh*4);
      f16x4 xh4 = *(const f16x4*)(xb + 2*8 + qh*4);
      int j = 16*(w*4+t) + jl;
      f32x4 hold = *(const f32x4*)(&hf[j][qh*4]);
      float hn[4];
      #pragma unroll
      for (int rr = 0; rr < 4; rr++){
        float dz = fz[t]  * shv[rr] * (float)accz[rr];
        float dr = fr2[t] * shv[rr] * (float)accr[rr];
        float dh = fh2[t] * shv[rr] * (float)acch[rr];
        float z    = sigmoidf_((float)xz4[rr] + dz);
        float r    = sigmoidf_((float)xr4g[rr] + dr);
        float cand = tanhf_((float)xh4[rr] + r*(brh[t] + dh));
        float hv = hold[rr];
        float h2 = z*hv + (1.0f-z)*cand;
        hn[rr] = (g < lenv[rr]) ? h2 : hv;   // per-batch freeze
      }
      if (q2 < 2){                            // real batches only
        f32x4 hw = {hn[0],hn[1],hn[2],hn[3]};
        *(f32x4*)(&hf[j][qh*4]) = hw;
        #pragma unroll
        for (int rr = 0; rr < 4; rr++){
          float qf = fmaxf(-127.f, fminf(127.f, rintf(hn[rr]*ishv[rr])));
          hqs[nxt][qh*4+rr][j] = (signed char)(int)qf;
        }
      }
    }
    // land prefetched x into the next buffer
    {
      _Float16* dst = &xbuf[nxt][w*1536 + L*8];
      *(f16x4*)(dst)=xr0;      *(f16x4*)(dst+4)=xr1;
      *(f16x4*)(dst+512)=xr2;  *(f16x4*)(dst+516)=xr3;
      *(f16x4*)(dst+1024)=xr4; *(f16x4*)(dst+1028)=xr5;
    }
    __syncthreads();                          // one barrier per step
    cur = nxt;
  }

  // out[b] = sigmoid(h . outW + outb)
  float part[4] = {0.f,0.f,0.f,0.f};
  #pragma unroll
  for (int t = 0; t < 4; t++){
    int j = 16*(w*4+t) + jl;
    float ow = outW[j];
    f32x4 hv = *(const f32x4*)(&hf[j][qh*4]);
    part[0] += hv[0]*ow; part[1] += hv[1]*ow;
    part[2] += hv[2]*ow; part[3] += hv[3]*ow;
  }
  if (q2 < 2){
    #pragma unroll
    for (int rr = 0; rr < 4; rr++) redq[qh*4+rr][w*16 + jl] = part[rr];
  }
  __syncthreads();
  if (tid < 8){
    float s = 0.f;
    for (int i = 0; i < 64; i++) s += redq[tid][i];
    out[tid] = sigmoidf_(s + outb[0]);
  }
}

extern "C" void kernel_launch(void* const* d_in, const int* in_sizes, int n_in,
                              void* d_out, int out_size, void* d_ws, size_t ws_size,
                              hipStream_t stream) {
  const float* demo   = (const float*)d_in[0];
  const float* times  = (const float*)d_in[1];
  const float* values = (const float*)d_in[2];
  const float* meas   = (const float*)d_in[3];
  const float* grid   = (const float*)d_in[4];
  const float* ksic   = (const float*)d_in[5];
  const float* crossW = (const float*)d_in[6];
  const float* dW1    = (const float*)d_in[7];
  const float* db1    = (const float*)d_in[8];
  const float* dW2    = (const float*)d_in[9];
  const float* db2    = (const float*)d_in[10];
  const float* gWx    = (const float*)d_in[11];
  const float* gWh    = (const float*)d_in[12];
  const float* gb     = (const float*)d_in[13];
  const float* outW   = (const float*)d_in[14];
  const float* outb   = (const float*)d_in[15];
  const int*   lens   = (const int*)d_in[16];
  float* out = (float*)d_out;

  float* ws   = (float*)d_ws;
  float* y    = ws;                        // B*D*G
  float* w    = y    + B_*D_*G_;
  float* ytr  = w    + B_*D_*G_;
  float* mean = ytr  + B_*D_*G_;
  float* h0   = mean + B_*D_;
  _Float16* xls = (_Float16*)(h0 + B_*H_);         // G*6144 f16 = 3MB
  int*   wfrag = (int*)(xls + (size_t)G_*XSTEP);   // 49152 dwords = 192KB
  float* wmx   = (float*)(wfrag + 16*3*4*64*4);    // 768 floats

  k_interp<<<B_*D_, 256, 0, stream>>>(times, values, meas, grid, ksic, y, w, ytr, mean);
  k_quant <<<12,    256, 0, stream>>>(gWh, wfrag, wmx);
  k_demo  <<<1,     256, 0, stream>>>(demo, dW1, db1, dW2, db2, h0);
  k_cross <<<B_*64, 256, 0, stream>>>(y, w, ytr, mean, crossW, gWx, gb, lens, xls);
  k_gru   <<<1,     256, 0, stream>>>(wfrag, wmx, gb, xls, h0, lens, outW, outb, out);
}

// Round 15
// 285.160 us; speedup vs baseline: 2.9869x; 2.9869x over previous
//
#include <hip/hip_runtime.h>
#include <hip/hip_bf16.h>

#define B_ 8
#define D_ 40
#define T_ 192
#define G_ 256
#define U_ 768   // 3*UNITS
#define H_ 256   // UNITS

__device__ inline float sigmoidf_(float x){
  return 1.0f/(1.0f+__expf(-x));
}
__device__ inline float tanhf_(float x){
  float ax = fabsf(x);
  float e = __expf(-2.0f*ax);
  float t = (1.0f-e)/(1.0f+e);
  return copysignf(t, x);
}
__device__ inline int sdot4(int a, int b, int c){
#if __has_builtin(__builtin_amdgcn_sdot4)
  return __builtin_amdgcn_sdot4(a, b, c, false);
#else
  int r = c;
  #pragma unroll
  for (int i=0;i<4;i++){
    int ai = (a << (24-8*i)) >> 24;
    int bi = (b << (24-8*i)) >> 24;
    r += ai*bi;
  }
  return r;
#endif
}
__device__ inline int pack4(int q0,int q1,int q2,int q3){
  return (q0&255) | ((q1&255)<<8) | ((q2&255)<<16) | ((q3&255)<<24);
}

// ---------------- Kernel 1: single-channel interp + per-(b,d) mean ----------
__global__ __launch_bounds__(256) void k_interp(
    const float* __restrict__ times, const float* __restrict__ values,
    const float* __restrict__ meas, const float* __restrict__ grid,
    const float* __restrict__ ksic,
    float* __restrict__ y, float* __restrict__ w, float* __restrict__ ytr,
    float* __restrict__ mean){
  int bd = blockIdx.x;            // b*D_+d
  int b = bd / D_, d = bd % D_;
  int g = threadIdx.x;
  __shared__ float tt[T_], vv[T_], mm[T_];
  __shared__ float red[256];
  if (g < T_){
    tt[g] = times[bd*T_+g];
    vv[g] = values[bd*T_+g];
    mm[g] = meas[bd*T_+g];
  }
  __syncthreads();
  float alpha = log1pf(__expf(ksic[d]));   // softplus
  float tg = grid[b*G_+g];
  float nmin = 3.4e38f;
  for (int t=0;t<T_;t++){
    if (mm[t] > 0.0f){
      float dd = tt[t]-tg;
      nmin = fminf(nmin, dd*dd);
    }
  }
  float s1=0.f, sv1=0.f, s10=0.f, sv10=0.f;
  for (int t=0;t<T_;t++){
    if (mm[t] > 0.0f){
      float dd = tt[t]-tg;
      float n = dd*dd - nmin;               // >= 0
      float e1  = __expf(-alpha*n);
      float e10 = __expf(-10.0f*alpha*n);
      s1 += e1;  sv1 += e1*vv[t];
      s10 += e10; sv10 += e10*vv[t];
    }
  }
  float yv = sv1/s1;
  float wv = -alpha*nmin + __logf(s1);
  y[bd*G_+g]   = yv;
  w[bd*G_+g]   = wv;
  ytr[bd*G_+g] = sv10/s10;
  red[g] = yv;
  __syncthreads();
  for (int s=128;s>0;s>>=1){
    if (g<s) red[g]+=red[g+s];
    __syncthreads();
  }
  if (g==0) mean[bd] = red[0]*(1.0f/(float)G_);
}

// ------- Kernel 2: cross-channel interp + feats + x_proj (4 g per block) ----
__global__ __launch_bounds__(256) void k_cross(
    const float* __restrict__ y, const float* __restrict__ w,
    const float* __restrict__ ytr, const float* __restrict__ mean,
    const float* __restrict__ crossW, const float* __restrict__ Wx,
    const float* __restrict__ gru_b, const int* __restrict__ lens,
    float* __restrict__ xproj){
  int blk = blockIdx.x;             // b*64 + gq
  int b = blk >> 6, gq = blk & 63;
  int g0 = gq*4;
  if (g0 >= lens[b]) return;        // whole quad unused
  __shared__ float wd[4][D_], yd[4][D_], ytrd[4][D_], md[D_];
  __shared__ float cc4[4][D_], feats[4][3*D_];
  __shared__ float wstat[4][2];
  int tid = threadIdx.x;
  int gg = tid / D_;
  int d  = tid % D_;
  if (tid < 4*D_){
    int idx = (b*D_+d)*G_ + g0 + gg;
    wd[gg][d]=w[idx]; yd[gg][d]=y[idx]; ytrd[gg][d]=ytr[idx];
  }
  if (tid < D_) md[tid] = mean[b*D_+tid];
  __syncthreads();
  if (tid < 4){
    float mx=-3.4e38f;
    for (int d2=0;d2<D_;d2++) mx = fmaxf(mx, wd[tid][d2]);
    float s=0.f;
    for (int d2=0;d2<D_;d2++) s += __expf(wd[tid][d2]-mx);
    wstat[tid][0]=mx; wstat[tid][1]=1.0f/s;
  }
  __syncthreads();
  if (tid < 4*D_){
    float sw = __expf(wd[gg][d]-wstat[gg][0])*wstat[gg][1];
    cc4[gg][d] = sw*(yd[gg][d]-md[d]);
  }
  __syncthreads();
  if (tid < 4*D_){
    float acc=0.f;
    for (int d2=0;d2<D_;d2++) acc += cc4[gg][d2]*crossW[d2*D_+d];
    float rep = acc + md[d];
    feats[gg][d]       = rep;
    feats[gg][D_+d]    = __expf(wd[gg][d]);
    feats[gg][2*D_+d]  = ytrd[gg][d]-rep;
  }
  __syncthreads();
  for (int jj=0;jj<3;jj++){
    int j = tid + jj*256;
    float bi = gru_b[j];
    float a0=bi, a1=bi, a2=bi, a3=bi;
    #pragma unroll 4
    for (int i=0;i<3*D_;i++){
      float wv = Wx[i*U_+j];        // one load feeds 4 g's
      a0 += feats[0][i]*wv;
      a1 += feats[1][i]*wv;
      a2 += feats[2][i]*wv;
      a3 += feats[3][i]*wv;
    }
    size_t base = ((size_t)(b*G_+g0))*U_ + j;
    xproj[base]       = a0;
    xproj[base+U_]    = a1;
    xproj[base+2*U_]  = a2;
    xproj[base+3*U_]  = a3;
  }
}

// ---------------- Kernel 3: demo MLP -> h0 ----------------------------------
__global__ __launch_bounds__(256) void k_demo(
    const float* __restrict__ demo, const float* __restrict__ W1,
    const float* __restrict__ b1, const float* __restrict__ W2,
    const float* __restrict__ b2, float* __restrict__ h0){
  __shared__ float dl[B_*16];
  __shared__ float hid[B_*H_];
  int u = threadIdx.x;
  if (u < B_*16) dl[u] = demo[u];
  __syncthreads();
  float acc[B_];
  #pragma unroll
  for (int b=0;b<B_;b++) acc[b]=b1[u];
  for (int i=0;i<16;i++){
    float w1 = W1[i*H_+u];
    #pragma unroll
    for (int b=0;b<B_;b++) acc[b] += dl[b*16+i]*w1;
  }
  #pragma unroll
  for (int b=0;b<B_;b++) hid[b*H_+u] = fmaxf(acc[b],0.f);
  __syncthreads();
  #pragma unroll
  for (int b=0;b<B_;b++) acc[b]=b2[u];
  for (int k=0;k<H_;k++){
    float w2 = W2[k*H_+u];
    #pragma unroll
    for (int b=0;b<B_;b++) acc[b] += hid[b*H_+k]*w2;
  }
  #pragma unroll
  for (int b=0;b<B_;b++) h0[b*H_+u]=acc[b];
}

// ---------------- Kernel 3b: quantize Wh -> int8 packed (parallel) ----------
__global__ __launch_bounds__(256) void k_quant(
    const float* __restrict__ Wh, int* __restrict__ wsq,
    float* __restrict__ wmaxs){
  int c0 = blockIdx.x*64;
  int rg = threadIdx.x >> 6;       // 0..3
  int cc = threadIdx.x & 63;
  int col = c0 + cc;
  float v[64];
  float mx = 0.f;
  #pragma unroll
  for (int r=0;r<64;r++){
    v[r] = Wh[(size_t)(rg*64+r)*U_ + col];
    mx = fmaxf(mx, fabsf(v[r]));
  }
  __shared__ float cm[4][64];
  cm[rg][cc] = mx;
  __syncthreads();
  float m = fmaxf(fmaxf(cm[0][cc],cm[1][cc]), fmaxf(cm[2][cc],cm[3][cc]));
  float iw = (m>0.f)? 127.0f/m : 0.f;
  if (rg==0) wmaxs[col] = m;
  #pragma unroll
  for (int k=0;k<16;k++){
    int q0=(int)rintf(v[4*k+0]*iw), q1=(int)rintf(v[4*k+1]*iw),
        q2=(int)rintf(v[4*k+2]*iw), q3=(int)rintf(v[4*k+3]*iw);
    wsq[(size_t)(rg*16+k)*U_ + col] = pack4(q0,q1,q2,q3);
  }
}

// ---------------- Kernel 4: masked GRU, int8, gate-per-wave-group -----------
// 768 threads / 12 waves / 3 waves per SIMD (the one int8 layout not yet
// tried; all ~850ns/step variants ran 1-2 waves/SIMD with latency exposed).
// Thread t owns full column col==t (gate=t>>8, unit j=t&255): 64 weight
// dwords + ~30 working ~= 95 regs < 170 HW ceiling at 3 waves/EU
// (waves_per_eu(3,3) pins; removes occupancy incentive per R10's lesson).
// Per step: all threads 64 sdot4 (full 256-deep dot, exact i32) + ONE x load
// xbase[g*U+t] (768-wide coalesced, 1-deep prefetch); r-threads publish
// sigmoid-ready pre-activation, h-threads publish hh_pre + their x; barrier;
// z-threads (t<256) run the gate chain, update f32 h, write quantized h
// byte; barrier. Gate tail has 1 busy wave/SIMD but dot phase (the bulk) now
// has 3-way wave interleave to hide LDS/chain latency.
__global__ __attribute__((amdgpu_flat_work_group_size(768,768), amdgpu_waves_per_eu(3,3)))
void k_gru(
    const int* __restrict__ wsq, const float* __restrict__ wmaxs,
    const float* __restrict__ gru_b,
    const float* __restrict__ xproj, const float* __restrict__ h0,
    const int* __restrict__ lens, const float* __restrict__ outW,
    const float* __restrict__ outb, float* __restrict__ out){
  int b = blockIdx.x;
  int t = threadIdx.x;
  int gt = t >> 8;                 // gate: 0=z 1=r 2=h (wave-uniform)
  int j  = t & 255;                // hidden unit

  __shared__ __align__(16) int hq[2][64];   // packed i8 h, double-buffered
  __shared__ float sPre[H_];       // r-gate pre-activation (from r-threads)
  __shared__ float hPre[H_];       // brh + fh*dot_h (from h-threads)
  __shared__ float xhv[H_];        // x_h value (from h-threads)
  __shared__ float red[H_];
  __shared__ float shs[2];         // [0]=inv_sh, [1]=s_h

  // ---- h0 + abs-max (fixed h scale; |h_new| <= max(|h_old|,1)) ----
  float hj = 0.f;
  if (t < H_){
    hj = h0[b*H_+t];
    red[t] = fabsf(hj);
  }
  __syncthreads();
  for (int st=128; st>0; st>>=1){
    if (t < st) red[t] = fmaxf(red[t], red[t+st]);
    __syncthreads();
  }
  if (t==0){
    float bound = fmaxf(red[0], 1.0f);
    shs[0] = 127.0f/bound;
    shs[1] = bound/127.0f;
  }
  __syncthreads();
  float inv_sh = shs[0];
  float s_h    = shs[1];

  // per-column dequant factor + recurrent bias (own column = t)
  float fc = wmaxs[t]*(1.0f/127.0f)*s_h;
  float br = gru_b[U_ + t];        // brz (gt0) / brr (gt1) / brh (gt2)

  // ---- load weights: 64 coalesced dwords (col == t) ----
  int wq[64];
  #pragma unroll
  for (int k=0;k<64;k++) wq[k] = wsq[(size_t)k*U_ + t];

  if (t < H_){
    float qf = fmaxf(-127.f, fminf(127.f, rintf(hj*inv_sh)));
    ((signed char*)hq[0])[t] = (signed char)(int)qf;
  }
  int len = lens[b];
  const float* xbase = xproj + (size_t)b*G_*U_;
  float xp = xbase[t];             // own-column x, 1-deep prefetch
  __syncthreads();

  for (int g=0; g<len; g++){
    float nx = 0.f;
    if (g+1 < len) nx = xbase[(size_t)(g+1)*U_ + t];
    const int4* hc = (const int4*)hq[g&1];
    // full 256-deep dot: 8 chunks x 2 int4 (bounded LDS-read hoisting),
    // 3 accumulator sub-chains
    int a0=0, a1=0, a2=0;
    #pragma unroll
    for (int c=0;c<8;c++){
      int4 u = hc[2*c], v = hc[2*c+1];
      a0=sdot4(u.x,wq[8*c+0],a0); a1=sdot4(u.y,wq[8*c+1],a1); a2=sdot4(u.z,wq[8*c+2],a2);
      a0=sdot4(u.w,wq[8*c+3],a0); a1=sdot4(v.x,wq[8*c+4],a1); a2=sdot4(v.y,wq[8*c+5],a2);
      a0=sdot4(v.z,wq[8*c+6],a0); a1=sdot4(v.w,wq[8*c+7],a1);
    }
    float dot = fc*(float)((a0+a1)+a2);
    if (gt == 1)      sPre[j] = xp + br + dot;   // r pre-activation
    else if (gt == 2){ hPre[j] = br + dot; xhv[j] = xp; }
    float myz = xp + br + dot;                   // z pre-activation (gt0)
    __syncthreads();
    if (gt == 0){
      float z    = sigmoidf_(myz);
      float r    = sigmoidf_(sPre[j]);
      float cand = tanhf_(xhv[j] + r*hPre[j]);
      hj = z*hj + (1.0f-z)*cand;
      float qf = fmaxf(-127.f, fminf(127.f, rintf(hj*inv_sh)));
      ((signed char*)hq[(g+1)&1])[j] = (signed char)(int)qf;
    }
    __syncthreads();
    xp = nx;
  }

  // out = sigmoid(h . outW + outb)  (h lives in z-threads)
  if (t < H_) red[t] = hj*outW[t];
  __syncthreads();
  for (int st=128;st>0;st>>=1){
    if (t<st) red[t]+=red[t+st];
    __syncthreads();
  }
  if (t==0) out[b] = sigmoidf_(red[0]+outb[0]);
}

extern "C" void kernel_launch(void* const* d_in, const int* in_sizes, int n_in,
                              void* d_out, int out_size, void* d_ws, size_t ws_size,
                              hipStream_t stream) {
  const float* demo   = (const float*)d_in[0];
  const float* times  = (const float*)d_in[1];
  const float* values = (const float*)d_in[2];
  const float* meas   = (const float*)d_in[3];
  const float* grid   = (const float*)d_in[4];
  const float* ksic   = (const float*)d_in[5];
  const float* crossW = (const float*)d_in[6];
  const float* dW1    = (const float*)d_in[7];
  const float* db1    = (const float*)d_in[8];
  const float* dW2    = (const float*)d_in[9];
  const float* db2    = (const float*)d_in[10];
  const float* gWx    = (const float*)d_in[11];
  const float* gWh    = (const float*)d_in[12];
  const float* gb     = (const float*)d_in[13];
  const float* outW   = (const float*)d_in[14];
  const float* outb   = (const float*)d_in[15];
  const int*   lens   = (const int*)d_in[16];
  float* out = (float*)d_out;

  float* ws   = (float*)d_ws;
  float* y    = ws;                        // B*D*G
  float* w    = y    + B_*D_*G_;
  float* ytr  = w    + B_*D_*G_;
  float* mean = ytr  + B_*D_*G_;
  float* h0   = mean + B_*D_;
  float* xprj = h0   + B_*H_;              // B*G*768
  int*   wsq  = (int*)(xprj + (size_t)B_*G_*U_);   // 64*768 dwords (192KB)
  float* wmx  = (float*)(wsq + 64*U_);             // 768 floats

  k_interp<<<B_*D_, 256, 0, stream>>>(times, values, meas, grid, ksic, y, w, ytr, mean);
  k_quant <<<12,    256, 0, stream>>>(gWh, wsq, wmx);
  k_demo  <<<1,     256, 0, stream>>>(demo, dW1, db1, dW2, db2, h0);
  k_cross <<<B_*64, 256, 0, stream>>>(y, w, ytr, mean, crossW, gWx, gb, lens, xprj);
  k_gru   <<<B_,    768, 0, stream>>>(wsq, wmx, gb, xprj, h0, lens, outW, outb, out);
}